// Round 5
// baseline (1571.110 us; speedup 1.0000x reference)
//
#include <hip/hip_runtime.h>
#include <hip/hip_bf16.h>
#include <cstdint>

typedef __attribute__((ext_vector_type(8))) short bf16x8;
typedef __attribute__((ext_vector_type(4))) float f32x4;

#define V_ 32000
#define E_ 512
#define H_ 1024
#define B_ 32
#define S_ 128

// ---- async global->LDS, 16B per lane (dest = wave-uniform base + lane*16) ----
typedef __attribute__((address_space(1))) unsigned int* gas1_t;
typedef __attribute__((address_space(3))) unsigned int* las3_t;
__device__ __forceinline__ void load_lds16(const void* g, void* l) {
  __builtin_amdgcn_global_load_lds((gas1_t)g, (las3_t)l, 16, 0, 0);
}

// ---- coherent h-state exchange primitives (proven R4) ----
__device__ __forceinline__ void ldx4_sc(bf16x8* d, const void* p) {
  asm volatile("global_load_dwordx4 %0, %1, off sc0 sc1" : "=v"(*d) : "v"(p) : "memory");
}
__device__ __forceinline__ unsigned ld_sc(const unsigned* p) {
  unsigned d;
  asm volatile("global_load_dword %0, %1, off sc0 sc1\n\ts_waitcnt vmcnt(0)"
               : "=v"(d) : "v"(p) : "memory");
  return d;
}
__device__ __forceinline__ void st_swap(unsigned* p, unsigned v) {
  asm volatile("global_atomic_swap %0, %1, off sc1" :: "v"(p), "v"(v) : "memory");
}
__device__ __forceinline__ void st_swap2(uint2* p, uint2 v) {
  asm volatile("global_atomic_swap_x2 %0, %1, off sc1" :: "v"(p), "v"(v) : "memory");
}
#define WAITVM(n)                                           \
  asm volatile("s_waitcnt vmcnt(" #n ")" ::: "memory");     \
  __builtin_amdgcn_sched_barrier(0)

__device__ __forceinline__ unsigned short bfbits(float x) {
  __hip_bfloat16 b = __float2bfloat16(x);
  union { __hip_bfloat16 b; unsigned short u; } c;
  c.b = b;
  return c.u;
}

// ---- transpose + f32->bf16 : src[R][C] -> dst[C][R] ----
__global__ __launch_bounds__(256) void transpose_f32_bf16(
    const float* __restrict__ src, __hip_bfloat16* __restrict__ dst, int R, int C) {
  __shared__ float tile[32][33];
  const int c0 = blockIdx.x << 5, r0 = blockIdx.y << 5;
  const int tx = threadIdx.x & 31, ty = threadIdx.x >> 5;  // ty 0..7
#pragma unroll
  for (int i = 0; i < 32; i += 8)
    tile[ty + i][tx] = src[(size_t)(r0 + ty + i) * C + (c0 + tx)];
  __syncthreads();
#pragma unroll
  for (int i = 0; i < 32; i += 8)
    dst[(size_t)(c0 + ty + i) * R + (r0 + tx)] = __float2bfloat16(tile[tx][ty + i]);
}

// ---- embedding gather -> bf16, rows ordered r = t*32 + b ----
__global__ __launch_bounds__(256) void gather_embed(
    const int* __restrict__ tokens, const float* __restrict__ emb,
    __hip_bfloat16* __restrict__ Xg) {
  const int r = blockIdx.x;          // 0..4095
  const int t = r >> 5, b = r & 31;
  const int tok = tokens[b * S_ + t];
  const float* e = emb + (size_t)tok * E_;
  __hip_bfloat16* o = Xg + (size_t)r * E_;
  for (int k = threadIdx.x; k < E_; k += 256) o[k] = __float2bfloat16(e[k]);
}

// ---- pre-arrange a [1024][1024] f32 weight (row=k, col=j) into MFMA B-fragment
//      linear bf16 layout: F[g:64][kb:32][lane:64][e:8] = W[kb*32+(lane>>4)*8+e][g*16+(lane&15)]
__global__ __launch_bounds__(256) void make_frag_w(
    const float* __restrict__ W, __hip_bfloat16* __restrict__ F) {
  const int idx = blockIdx.x * 256 + threadIdx.x;  // 64*32*64 = 131072 total
  const int lane = idx & 63, kb = (idx >> 6) & 31, g = idx >> 11;
  const int j = (g << 4) + (lane & 15);
  const int kbase = (kb << 5) + ((lane >> 4) << 3);
  __hip_bfloat16* o = F + (size_t)idx * 8;
#pragma unroll
  for (int e = 0; e < 8; ++e) o[e] = __float2bfloat16(W[(size_t)(kbase + e) * H_ + j]);
}

// ---- m97-style bf16 MFMA GEMM + bijective XCD swizzle: C = A * Bt^T + bias ----
__global__ __launch_bounds__(256) void gemm_bf16_tn(
    const __hip_bfloat16* __restrict__ A,   // [M][K] row-major
    const __hip_bfloat16* __restrict__ Bt,  // [N][K] row-major
    const float* __restrict__ bias,         // [N]
    float* __restrict__ C,                  // [M][N]
    int M, int N, int K) {
  __shared__ __hip_bfloat16 ldsA[128 * 64];
  __shared__ __hip_bfloat16 ldsB[128 * 64];
  // XCD-aware swizzle (requires nwg % 8 == 0; both launches satisfy this)
  const int nwg = gridDim.x * gridDim.y;
  int L = blockIdx.y * gridDim.x + blockIdx.x;
  L = ((L & 7) * (nwg >> 3)) + (L >> 3);
  const int m0 = (L / gridDim.x) << 7;
  const int n0 = (L % gridDim.x) << 7;
  const int tid = threadIdx.x, wave = tid >> 6, lane = tid & 63;
  const int wr = wave >> 1, wc = wave & 1;
  f32x4 acc[4][4];
#pragma unroll
  for (int i = 0; i < 4; ++i)
#pragma unroll
    for (int jj = 0; jj < 4; ++jj) acc[i][jj] = (f32x4){0.f, 0.f, 0.f, 0.f};

  for (int k0 = 0; k0 < K; k0 += 64) {
#pragma unroll
    for (int i = 0; i < 4; ++i) {
      const int c = i * 4 + wave;          // chunk 0..15 (1KB each)
      const int idx = (c << 6) + lane;     // 0..1023
      const int row = idx >> 3, kk = (idx & 7) << 3;
      load_lds16(A + (size_t)(m0 + row) * K + (k0 + kk), ldsA + c * 512);
      load_lds16(Bt + (size_t)(n0 + row) * K + (k0 + kk), ldsB + c * 512);
    }
    __syncthreads();
#pragma unroll
    for (int ks = 0; ks < 2; ++ks) {
      bf16x8 af[4], bfr[4];
#pragma unroll
      for (int mi = 0; mi < 4; ++mi)
        af[mi] = *(const bf16x8*)(ldsA + (((wr << 6) + (mi << 4) + (lane & 15)) << 6) +
                                  (ks << 5) + ((lane >> 4) << 3));
#pragma unroll
      for (int ni = 0; ni < 4; ++ni)
        bfr[ni] = *(const bf16x8*)(ldsB + (((wc << 6) + (ni << 4) + (lane & 15)) << 6) +
                                   (ks << 5) + ((lane >> 4) << 3));
#pragma unroll
      for (int mi = 0; mi < 4; ++mi)
#pragma unroll
        for (int ni = 0; ni < 4; ++ni)
          acc[mi][ni] =
              __builtin_amdgcn_mfma_f32_16x16x32_bf16(af[mi], bfr[ni], acc[mi][ni], 0, 0, 0);
    }
    __syncthreads();
  }
#pragma unroll
  for (int mi = 0; mi < 4; ++mi) {
#pragma unroll
    for (int ni = 0; ni < 4; ++ni) {
      const int n = n0 + (wc << 6) + (ni << 4) + (lane & 15);
      const float bn = bias[n];
#pragma unroll
      for (int r = 0; r < 4; ++r) {
        const int m = m0 + (wr << 6) + (mi << 4) + ((lane >> 4) << 2) + r;
        C[(size_t)m * N + n] = acc[mi][ni][r] + bn;
      }
    }
  }
}

// ---- recurrence: 64 WGs x 256 thr. h-state: swap_x2 publish + sc0/sc1 loads.
// Flag-array barrier: per-WG 64B-padded flag (parallel arrival), wave-0 parallel poll.
__global__ __launch_bounds__(256, 1) void rnn_recur(
    const __hip_bfloat16* __restrict__ U0f, const __hip_bfloat16* __restrict__ W1f,
    const __hip_bfloat16* __restrict__ U1f, const float* __restrict__ xw,  // [128][32][1024]
    const float* __restrict__ b1,
    __hip_bfloat16* __restrict__ h0buf,  // [2][32][1024]
    __hip_bfloat16* __restrict__ h1buf,  // [2][32][1024]
    __hip_bfloat16* __restrict__ Y,      // [4096][1024], row = b*128 + t
    unsigned* __restrict__ flags) {      // [64*16] dwords, zeroed before launch
  __shared__ __hip_bfloat16 sm[3 * 16384];  // 96KB: U0 slab | W1 slab | U1 slab
  __hip_bfloat16* s_u0 = sm;
  __hip_bfloat16* s_w1 = sm + 16384;
  __hip_bfloat16* s_u1 = sm + 32768;
  const int g = blockIdx.x;  // column group: cols g*16 .. g*16+15
  const int tid = threadIdx.x, wave = tid >> 6, lane = tid & 63;
  const int mi = wave & 1;  // batch-frag: rows mi*16..mi*16+15

  {  // stage the 3 weight slabs (32KB each) once
    const size_t base = (size_t)g * 16384;
    const uint4* su0 = (const uint4*)(U0f + base);
    const uint4* sw1 = (const uint4*)(W1f + base);
    const uint4* su1 = (const uint4*)(U1f + base);
    uint4* d0 = (uint4*)s_u0;
    uint4* d1 = (uint4*)s_w1;
    uint4* d2 = (uint4*)s_u1;
    for (int i = tid; i < 2048; i += 256) {
      d0[i] = su0[i];
      d1[i] = sw1[i];
      d2[i] = su1[i];
    }
  }
  __syncthreads();

  const int j = (g << 4) + (lane & 15);
  const int rowbase = (mi << 4) + ((lane >> 4) << 2);
  const int arow_off = ((mi << 4) + (lane & 15)) * H_ + ((lane >> 4) << 3);
  const float b1j = b1[j];
  const int rs = lane & 3;  // which of the 4 acc rows this lane publishes

  for (int p = 0; p <= S_; ++p) {
    if (wave < 2) {
      if (p < S_) {
        const __hip_bfloat16* ar = h0buf + (((p & 1) ^ 1) << 15) + arow_off;  // h0(p-1)
        bf16x8 xa[32];
#pragma unroll
        for (int kc = 0; kc < 16; ++kc) ldx4_sc(&xa[kc], ar + (kc << 5));
#pragma unroll
        for (int kc = 16; kc < 32; ++kc) ldx4_sc(&xa[kc], ar + (kc << 5));
        f32x4 a0 = {0.f, 0.f, 0.f, 0.f}, a1 = {0.f, 0.f, 0.f, 0.f};
        WAITVM(16);
#pragma unroll
        for (int kc = 0; kc < 16; ++kc) {
          bf16x8 w = *(const bf16x8*)(s_u0 + (((kc << 6) + lane) << 3));
          a0 = __builtin_amdgcn_mfma_f32_16x16x32_bf16(xa[kc], w, a0, 0, 0, 0);
        }
        WAITVM(0);
#pragma unroll
        for (int kc = 16; kc < 32; ++kc) {
          bf16x8 w = *(const bf16x8*)(s_u0 + (((kc << 6) + lane) << 3));
          a1 = __builtin_amdgcn_mfma_f32_16x16x32_bf16(xa[kc], w, a1, 0, 0, 0);
        }
        f32x4 acc = a0 + a1;
        const float* xrow = xw + ((size_t)p << 15);
        float f[4];
#pragma unroll
        for (int r = 0; r < 4; ++r) f[r] = tanhf(acc[r] + xrow[(rowbase + r) * H_ + j]);
        // pack 4 cols x 4 rows into uint2 per row via 2 shfl_xor rounds
        uint2 v2[4];
#pragma unroll
        for (int r = 0; r < 4; ++r) {
          const float o = __shfl_xor(f[r], 1);
          const float lo = (lane & 1) ? o : f[r];
          const float hi = (lane & 1) ? f[r] : o;
          const unsigned pk = (unsigned)bfbits(lo) | ((unsigned)bfbits(hi) << 16);
          const unsigned q2 = __shfl_xor(pk, 2);
          v2[r].x = (j & 2) ? q2 : pk;
          v2[r].y = (j & 2) ? pk : q2;
        }
        uint2 vsel = rs == 0 ? v2[0] : rs == 1 ? v2[1] : rs == 2 ? v2[2] : v2[3];
        uint2* h4 = (uint2*)(h0buf + ((p & 1) << 15));
        st_swap2(h4 + (rowbase + rs) * (H_ / 4) + (j >> 2), vsel);
      }
    } else {
      if (p >= 1) {
        const __hip_bfloat16* ar0 = h0buf + (((p & 1) ^ 1) << 15) + arow_off;  // h0(p-1)
        const __hip_bfloat16* ar1 = h1buf + ((p & 1) << 15) + arow_off;        // h1(p-2)
        bf16x8 pa[32], pb[32];
#pragma unroll
        for (int kc = 0; kc < 16; ++kc) ldx4_sc(&pa[kc], ar0 + (kc << 5));  // A0
#pragma unroll
        for (int kc = 16; kc < 32; ++kc) ldx4_sc(&pa[kc], ar0 + (kc << 5));  // A1
#pragma unroll
        for (int kc = 0; kc < 16; ++kc) ldx4_sc(&pb[kc], ar1 + (kc << 5));  // B0
        f32x4 a0 = {0.f, 0.f, 0.f, 0.f}, a1 = {0.f, 0.f, 0.f, 0.f};
        f32x4 a2 = {0.f, 0.f, 0.f, 0.f}, a3 = {0.f, 0.f, 0.f, 0.f};
        WAITVM(32);  // A0 done
#pragma unroll
        for (int kc = 0; kc < 16; ++kc) {
          bf16x8 w = *(const bf16x8*)(s_w1 + (((kc << 6) + lane) << 3));
          a0 = __builtin_amdgcn_mfma_f32_16x16x32_bf16(pa[kc], w, a0, 0, 0, 0);
        }
#pragma unroll
        for (int kc = 16; kc < 32; ++kc) ldx4_sc(&pb[kc], ar1 + (kc << 5));  // B1
        WAITVM(32);  // A1 done
#pragma unroll
        for (int kc = 16; kc < 32; ++kc) {
          bf16x8 w = *(const bf16x8*)(s_w1 + (((kc << 6) + lane) << 3));
          a1 = __builtin_amdgcn_mfma_f32_16x16x32_bf16(pa[kc], w, a1, 0, 0, 0);
        }
        WAITVM(16);  // B0 done
#pragma unroll
        for (int kc = 0; kc < 16; ++kc) {
          bf16x8 w = *(const bf16x8*)(s_u1 + (((kc << 6) + lane) << 3));
          a2 = __builtin_amdgcn_mfma_f32_16x16x32_bf16(pb[kc], w, a2, 0, 0, 0);
        }
        WAITVM(0);  // B1 done
#pragma unroll
        for (int kc = 16; kc < 32; ++kc) {
          bf16x8 w = *(const bf16x8*)(s_u1 + (((kc << 6) + lane) << 3));
          a3 = __builtin_amdgcn_mfma_f32_16x16x32_bf16(pb[kc], w, a3, 0, 0, 0);
        }
        f32x4 acc = (a0 + a1) + (a2 + a3);
        const int t = p - 1;
        float f[4];
#pragma unroll
        for (int r = 0; r < 4; ++r) f[r] = tanhf(acc[r] + b1j);
        uint2 v2[4];
#pragma unroll
        for (int r = 0; r < 4; ++r) {
          const float o = __shfl_xor(f[r], 1);
          const float lo = (lane & 1) ? o : f[r];
          const float hi = (lane & 1) ? f[r] : o;
          const unsigned pk = (unsigned)bfbits(lo) | ((unsigned)bfbits(hi) << 16);
          const unsigned q2 = __shfl_xor(pk, 2);
          v2[r].x = (j & 2) ? q2 : pk;
          v2[r].y = (j & 2) ? pk : q2;
        }
        uint2 vsel = rs == 0 ? v2[0] : rs == 1 ? v2[1] : rs == 2 ? v2[2] : v2[3];
        const int bb = rowbase + rs;
        uint2* h4 = (uint2*)(h1buf + (((p - 1) & 1) << 15));
        st_swap2(h4 + bb * (H_ / 4) + (j >> 2), vsel);
        uint2* Y4 = (uint2*)Y;
        Y4[((size_t)bb * S_ + t) * (H_ / 4) + (j >> 2)] = vsel;  // normal cached store
      }
    }
    if (p < S_) {
      // flag-array barrier: drain -> WG-arrive (own 64B word) -> parallel poll
      WAITVM(0);
      __syncthreads();
      if (tid == 0) st_swap(flags + g * 16, (unsigned)(p + 1));
      if (wave == 0) {
        unsigned v;
        do { v = ld_sc(flags + lane * 16); } while (__any(v <= (unsigned)p));
      }
      __syncthreads();
    }
  }
}

extern "C" void kernel_launch(void* const* d_in, const int* in_sizes, int n_in, void* d_out,
                              int out_size, void* d_ws, size_t ws_size, hipStream_t stream) {
  const int* tokens = (const int*)d_in[0];
  const float* emb = (const float*)d_in[1];
  const float* W0 = (const float*)d_in[2];
  const float* U0 = (const float*)d_in[3];
  const float* b0 = (const float*)d_in[4];
  const float* W1 = (const float*)d_in[5];
  const float* U1 = (const float*)d_in[6];
  const float* b1 = (const float*)d_in[7];
  const float* Wd = (const float*)d_in[8];
  const float* bd = (const float*)d_in[9];
  float* out = (float*)d_out;

  char* ws = (char*)d_ws;
  __hip_bfloat16* Wdt = (__hip_bfloat16*)ws;  ws += (size_t)V_ * H_ * 2;       // 64MB
  __hip_bfloat16* W0t = (__hip_bfloat16*)ws;  ws += (size_t)H_ * E_ * 2;       // 1MB
  __hip_bfloat16* Xg = (__hip_bfloat16*)ws;   ws += (size_t)4096 * E_ * 2;     // 4MB
  __hip_bfloat16* U0f = (__hip_bfloat16*)ws;  ws += (size_t)H_ * H_ * 2;       // 2MB
  __hip_bfloat16* W1f = (__hip_bfloat16*)ws;  ws += (size_t)H_ * H_ * 2;       // 2MB
  __hip_bfloat16* U1f = (__hip_bfloat16*)ws;  ws += (size_t)H_ * H_ * 2;       // 2MB
  float* xw = (float*)ws;                     ws += (size_t)4096 * H_ * 4;     // 16MB
  __hip_bfloat16* h0buf = (__hip_bfloat16*)ws; ws += 2 * B_ * H_ * 2;          // 128KB
  __hip_bfloat16* h1buf = (__hip_bfloat16*)ws; ws += 2 * B_ * H_ * 2;          // 128KB
  __hip_bfloat16* Y = (__hip_bfloat16*)ws;    ws += (size_t)4096 * H_ * 2;     // 8MB
  unsigned* flags = (unsigned*)ws;            ws += 4096;

  // prep
  transpose_f32_bf16<<<dim3(V_ / 32, H_ / 32), 256, 0, stream>>>(Wd, Wdt, H_, V_);
  transpose_f32_bf16<<<dim3(H_ / 32, E_ / 32), 256, 0, stream>>>(W0, W0t, E_, H_);
  gather_embed<<<4096, 256, 0, stream>>>(tokens, emb, Xg);
  make_frag_w<<<512, 256, 0, stream>>>(U0, U0f);
  make_frag_w<<<512, 256, 0, stream>>>(W1, W1f);
  make_frag_w<<<512, 256, 0, stream>>>(U1, U1f);
  hipMemsetAsync(h0buf, 0, (size_t)4 * B_ * H_ * 2, stream);  // h0buf + h1buf
  hipMemsetAsync(flags, 0, 4096, stream);

  // xw = Xg @ W0 + b0   (M=4096, N=1024, K=512)  — nwg=256, %8==0
  gemm_bf16_tn<<<dim3(H_ / 128, 4096 / 128), 256, 0, stream>>>(Xg, W0t, b0, xw, 4096, H_, E_);

  // recurrence — normal launch; 64 WGs co-resident by construction
  rnn_recur<<<64, 256, 0, stream>>>(U0f, W1f, U1f, xw, b1, h0buf, h1buf, Y, flags);

  // logits = Y @ Wd + bd   (M=4096, N=32000, K=1024)  — nwg=8000, %8==0
  gemm_bf16_tn<<<dim3(V_ / 128, 4096 / 128), 256, 0, stream>>>(Y, Wdt, bd, out, 4096, V_, H_);
}

// Round 7
// 1379.538 us; speedup vs baseline: 1.1389x; 1.1389x over previous
//
#include <hip/hip_runtime.h>
#include <hip/hip_bf16.h>
#include <cstdint>

typedef __attribute__((ext_vector_type(8))) short bf16x8;
typedef __attribute__((ext_vector_type(4))) float f32x4;
typedef __attribute__((ext_vector_type(4))) unsigned int u32x4;

#define V_ 32000
#define E_ 512
#define H_ 1024
#define B_ 32
#define S_ 128

#define L1WG 16   // 16 WGs x 64 cols (layer 1)
#define L2WG 32   // 32 WGs x 32 cols (layer 2)
#define NWGS 48

// ---- async global->LDS, 16B per lane (dest = wave-uniform base + lane*16) ----
typedef __attribute__((address_space(1))) unsigned int* gas1_t;
typedef __attribute__((address_space(3))) unsigned int* las3_t;
__device__ __forceinline__ void load_lds16(const void* g, void* l) {
  __builtin_amdgcn_global_load_lds((gas1_t)g, (las3_t)l, 16, 0, 0);
}

// ---- coherent h-state exchange primitives (visibility proven R4/R5) ----
__device__ __forceinline__ void ldx4_sc(u32x4* d, const void* p) {
  asm volatile("global_load_dwordx4 %0, %1, off sc0 sc1" : "=v"(*d) : "v"(p) : "memory");
}
__device__ __forceinline__ unsigned ld_sc(const unsigned* p) {
  unsigned d;
  asm volatile("global_load_dword %0, %1, off sc0 sc1\n\ts_waitcnt vmcnt(0)"
               : "=v"(d) : "v"(p) : "memory");
  return d;
}
__device__ __forceinline__ void st_swap(unsigned* p, unsigned v) {
  asm volatile("global_atomic_swap %0, %1, off sc1" :: "v"(p), "v"(v) : "memory");
}
__device__ __forceinline__ void st_swap2(uint2* p, uint2 v) {
  asm volatile("global_atomic_swap_x2 %0, %1, off sc1" :: "v"(p), "v"(v) : "memory");
}
#define WAITVM0()                                     \
  asm volatile("s_waitcnt vmcnt(0)" ::: "memory");    \
  __builtin_amdgcn_sched_barrier(0)

__device__ __forceinline__ unsigned short bfbits(float x) {
  __hip_bfloat16 b = __float2bfloat16(x);
  union { __hip_bfloat16 b; unsigned short u; } c;
  c.b = b;
  return c.u;
}

// pack 4 rows x 4 cols into one uint2 per lane (2 shfl_xor rounds) — proven R5
__device__ __forceinline__ uint2 pack_rows(const float f[4], int lane, int j) {
  uint2 v2[4];
#pragma unroll
  for (int r = 0; r < 4; ++r) {
    const float o = __shfl_xor(f[r], 1);
    const float lo = (lane & 1) ? o : f[r];
    const float hi = (lane & 1) ? f[r] : o;
    const unsigned pk = (unsigned)bfbits(lo) | ((unsigned)bfbits(hi) << 16);
    const unsigned q2 = __shfl_xor(pk, 2);
    v2[r].x = (j & 2) ? q2 : pk;
    v2[r].y = (j & 2) ? pk : q2;
  }
  const int rs = lane & 3;
  return rs == 0 ? v2[0] : rs == 1 ? v2[1] : rs == 2 ? v2[2] : v2[3];
}

// ---- transpose + f32->bf16 : src[R][C] -> dst[C][R] ----
__global__ __launch_bounds__(256) void transpose_f32_bf16(
    const float* __restrict__ src, __hip_bfloat16* __restrict__ dst, int R, int C) {
  __shared__ float tile[32][33];
  const int c0 = blockIdx.x << 5, r0 = blockIdx.y << 5;
  const int tx = threadIdx.x & 31, ty = threadIdx.x >> 5;
#pragma unroll
  for (int i = 0; i < 32; i += 8)
    tile[ty + i][tx] = src[(size_t)(r0 + ty + i) * C + (c0 + tx)];
  __syncthreads();
#pragma unroll
  for (int i = 0; i < 32; i += 8)
    dst[(size_t)(c0 + ty + i) * R + (r0 + tx)] = __float2bfloat16(tile[tx][ty + i]);
}

// ---- embedding gather -> bf16, rows ordered r = t*32 + b ----
__global__ __launch_bounds__(256) void gather_embed(
    const int* __restrict__ tokens, const float* __restrict__ emb,
    __hip_bfloat16* __restrict__ Xg) {
  const int r = blockIdx.x;
  const int t = r >> 5, b = r & 31;
  const int tok = tokens[b * S_ + t];
  const float* e = emb + (size_t)tok * E_;
  __hip_bfloat16* o = Xg + (size_t)r * E_;
  for (int k = threadIdx.x; k < E_; k += 256) o[k] = __float2bfloat16(e[k]);
}

// ---- [1024][1024] f32 weight -> MFMA B-fragment-linear bf16 ----
// F[g16][kb][lane][e] = W[kb*32+(lane>>4)*8+e][g16*16+(lane&15)]
__global__ __launch_bounds__(256) void make_frag_w(
    const float* __restrict__ W, __hip_bfloat16* __restrict__ F) {
  const int idx = blockIdx.x * 256 + threadIdx.x;
  const int lane = idx & 63, kb = (idx >> 6) & 31, g = idx >> 11;
  const int j = (g << 4) + (lane & 15);
  const int kbase = (kb << 5) + ((lane >> 4) << 3);
  __hip_bfloat16* o = F + (size_t)idx * 8;
#pragma unroll
  for (int e = 0; e < 8; ++e) o[e] = __float2bfloat16(W[(size_t)(kbase + e) * H_ + j]);
}

// ---- m97-style bf16 MFMA GEMM + bijective XCD swizzle: C = A * Bt^T + bias ----
__global__ __launch_bounds__(256) void gemm_bf16_tn(
    const __hip_bfloat16* __restrict__ A, const __hip_bfloat16* __restrict__ Bt,
    const float* __restrict__ bias, float* __restrict__ C, int M, int N, int K) {
  __shared__ __hip_bfloat16 ldsA[128 * 64];
  __shared__ __hip_bfloat16 ldsB[128 * 64];
  const int nwg = gridDim.x * gridDim.y;
  int L = blockIdx.y * gridDim.x + blockIdx.x;
  L = ((L & 7) * (nwg >> 3)) + (L >> 3);
  const int m0 = (L / gridDim.x) << 7;
  const int n0 = (L % gridDim.x) << 7;
  const int tid = threadIdx.x, wave = tid >> 6, lane = tid & 63;
  const int wr = wave >> 1, wc = wave & 1;
  f32x4 acc[4][4];
#pragma unroll
  for (int i = 0; i < 4; ++i)
#pragma unroll
    for (int jj = 0; jj < 4; ++jj) acc[i][jj] = (f32x4){0.f, 0.f, 0.f, 0.f};

  for (int k0 = 0; k0 < K; k0 += 64) {
#pragma unroll
    for (int i = 0; i < 4; ++i) {
      const int c = i * 4 + wave;
      const int idx = (c << 6) + lane;
      const int row = idx >> 3, kk = (idx & 7) << 3;
      load_lds16(A + (size_t)(m0 + row) * K + (k0 + kk), ldsA + c * 512);
      load_lds16(Bt + (size_t)(n0 + row) * K + (k0 + kk), ldsB + c * 512);
    }
    __syncthreads();
#pragma unroll
    for (int ks = 0; ks < 2; ++ks) {
      bf16x8 af[4], bfr[4];
#pragma unroll
      for (int mi = 0; mi < 4; ++mi)
        af[mi] = *(const bf16x8*)(ldsA + (((wr << 6) + (mi << 4) + (lane & 15)) << 6) +
                                  (ks << 5) + ((lane >> 4) << 3));
#pragma unroll
      for (int ni = 0; ni < 4; ++ni)
        bfr[ni] = *(const bf16x8*)(ldsB + (((wc << 6) + (ni << 4) + (lane & 15)) << 6) +
                                   (ks << 5) + ((lane >> 4) << 3));
#pragma unroll
      for (int mi = 0; mi < 4; ++mi)
#pragma unroll
        for (int ni = 0; ni < 4; ++ni)
          acc[mi][ni] =
              __builtin_amdgcn_mfma_f32_16x16x32_bf16(af[mi], bfr[ni], acc[mi][ni], 0, 0, 0);
    }
    __syncthreads();
  }
#pragma unroll
  for (int mi = 0; mi < 4; ++mi) {
#pragma unroll
    for (int ni = 0; ni < 4; ++ni) {
      const int n = n0 + (wc << 6) + (ni << 4) + (lane & 15);
      const float bn = bias[n];
#pragma unroll
      for (int r = 0; r < 4; ++r) {
        const int m = m0 + (wr << 6) + (mi << 4) + ((lane >> 4) << 2) + r;
        C[(size_t)m * N + n] = acc[mi][ni][r] + bn;
      }
    }
  }
}

// ============================================================================
// Recurrence: 48 WGs x 512 thr. Traffic-reduced structure:
//  - weights live in per-wave VGPRs (128 regs = 16-col frag slice), not LDS
//  - h-state staged ONCE per WG into LDS (XOR-swizzled) and shared by 8 waves
//  - WGs 0..15 (L1-class): 64 cols of layer 1; stage h0 only (64KB)
//  - WGs 16..47 (L2-class): 32 cols of layer 2; stage h0+h1 (128KB);
//    W1-waves and U1-waves pair-exchange f32 partials via 4KB LDS pad
// Sync = R4/R5 proven: atomic-swap publish -> vmcnt0 -> flag swap -> sc poll.
// ============================================================================
__global__ __launch_bounds__(512, 2) void rnn_recur(
    const __hip_bfloat16* __restrict__ U0f, const __hip_bfloat16* __restrict__ W1f,
    const __hip_bfloat16* __restrict__ U1f, const float* __restrict__ xw,  // [128][32][1024]
    const float* __restrict__ b1,
    __hip_bfloat16* __restrict__ h0buf,  // [2][32][1024]
    __hip_bfloat16* __restrict__ h1buf,  // [2][32][1024]
    __hip_bfloat16* __restrict__ Y,      // [4096][1024], row = b*128 + t
    unsigned* __restrict__ flags) {      // [48*16] dwords, zeroed before launch
  __shared__ char smem[135168];  // sA0 64KB | sA1 64KB | pad 4KB
  char* sA0 = smem;
  char* sA1 = smem + 65536;
  float* pad = (float*)(smem + 131072);

  const int g = blockIdx.x;
  const bool isL1 = (g < L1WG);
  const int tid = threadIdx.x, wave = tid >> 6, lane = tid & 63;
  const int mi = wave & 1;
  const int cg = isL1 ? (wave >> 1) : ((wave >> 1) & 1);
  const int mat = isL1 ? 0 : (wave >> 2);  // L2: 0 = W1-wave, 1 = U1-wave
  const int colbase = isL1 ? (g << 6) : ((g - L1WG) << 5);
  const int j = colbase + (cg << 4) + (lane & 15);
  const int gg = (colbase >> 4) + cg;  // global 16-col group 0..63
  const int rowbase = (mi << 4) + ((lane >> 4) << 2);
  const int rs = lane & 3;
  const int ra = (mi << 4) + (lane & 15);  // A-frag row this lane reads
  const float b1j = b1[j];

  // ---- preload this wave's weight slice into VGPRs (frag-linear, cached) ----
  const __hip_bfloat16* wb = isL1 ? U0f : (mat == 0 ? W1f : U1f);
  bf16x8 wfr[32];
#pragma unroll
  for (int kb = 0; kb < 32; ++kb)
    wfr[kb] = *(const bf16x8*)(wb + (size_t)((((gg << 5) + kb) << 6) + lane) * 8);

  // sA1 <- 0 (h1(-1) == 0) for L2-class
  if (!isL1) {
    for (int i = tid; i < 4096; i += 512) *(uint4*)(sA1 + i * 16) = (uint4){0u, 0u, 0u, 0u};
  }
  __syncthreads();

  const int plast = isL1 ? (S_ - 1) : S_;
  for (int p = 0; p <= plast; ++p) {
    if (p >= 1) {
      // ---- poll: all 48 WG flags >= p ----
      const unsigned* fp = flags + ((lane < NWGS ? lane : NWGS - 1) << 4);
      unsigned v;
      do { v = ld_sc(fp); } while (__any(v < (unsigned)p));
      // ---- stage h0(p-1) [+ h1(p-2)] into LDS, swizzled ----
      {
        const char* src0 = (const char*)(h0buf + (((p - 1) & 1) << 15));
        u32x4 t0[8], t1[8];
#pragma unroll
        for (int i = 0; i < 8; ++i) ldx4_sc(&t0[i], src0 + (size_t)(((i << 9) + tid) << 4));
        if (!isL1 && p >= 2) {
          const char* src1 = (const char*)(h1buf + (((p - 2) & 1) << 15));
#pragma unroll
          for (int i = 0; i < 8; ++i) ldx4_sc(&t1[i], src1 + (size_t)(((i << 9) + tid) << 4));
        }
        WAITVM0();
#pragma unroll
        for (int i = 0; i < 8; ++i) {
          const int c = (i << 9) + tid;
          const int row = c >> 7, colb = (c & 127) << 4;
          *(u32x4*)(sA0 + (row << 11) + (colb ^ ((row & 7) << 4))) = t0[i];
        }
        if (!isL1 && p >= 2) {
#pragma unroll
          for (int i = 0; i < 8; ++i) {
            const int c = (i << 9) + tid;
            const int row = c >> 7, colb = (c & 127) << 4;
            *(u32x4*)(sA1 + (row << 11) + (colb ^ ((row & 7) << 4))) = t1[i];
          }
        }
      }
      __syncthreads();
    }

    if (isL1) {
      // ---- layer 1: h0(p) = tanh(xw[p] + h0(p-1)@U0) ----
      f32x4 acc = {0.f, 0.f, 0.f, 0.f};
      if (p >= 1) {
#pragma unroll
        for (int kb = 0; kb < 32; ++kb) {
          bf16x8 a = *(const bf16x8*)(
              sA0 + (ra << 11) + ((((kb << 6) + ((lane >> 4) << 4))) ^ ((ra & 7) << 4)));
          acc = __builtin_amdgcn_mfma_f32_16x16x32_bf16(a, wfr[kb], acc, 0, 0, 0);
        }
      }
      const float* xrow = xw + ((size_t)p << 15);
      float f[4];
#pragma unroll
      for (int r = 0; r < 4; ++r) f[r] = tanhf(acc[r] + xrow[(rowbase + r) * H_ + j]);
      uint2 vsel = pack_rows(f, lane, j);
      uint2* h4 = (uint2*)(h0buf + ((p & 1) << 15));
      st_swap2(h4 + (rowbase + rs) * (H_ / 4) + (j >> 2), vsel);
    } else if (p >= 1) {
      // ---- layer 2: h1(p-1) = tanh(h0(p-1)@W1 + h1(p-2)@U1 + b1) ----
      const char* sA = (mat == 0) ? sA0 : sA1;
      f32x4 acc = {0.f, 0.f, 0.f, 0.f};
#pragma unroll
      for (int kb = 0; kb < 32; ++kb) {
        bf16x8 a = *(const bf16x8*)(
            sA + (ra << 11) + ((((kb << 6) + ((lane >> 4) << 4))) ^ ((ra & 7) << 4)));
        acc = __builtin_amdgcn_mfma_f32_16x16x32_bf16(a, wfr[kb], acc, 0, 0, 0);
      }
      const int pair = wave & 3;  // (mi, cg) pair id
      if (mat == 0) *(f32x4*)(pad + pair * 256 + lane * 4) = acc;
      __syncthreads();  // W-partial ready (uniform within L2-class block)
      if (mat == 1) {
        f32x4 accW = *(const f32x4*)(pad + pair * 256 + lane * 4);
        const int t = p - 1;
        float f[4];
#pragma unroll
        for (int r = 0; r < 4; ++r) f[r] = tanhf(acc[r] + accW[r] + b1j);
        uint2 vsel = pack_rows(f, lane, j);
        const int bb = rowbase + rs;
        ((uint2*)Y)[((size_t)bb * S_ + t) * (H_ / 4) + (j >> 2)] = vsel;  // cached
        uint2* h4 = (uint2*)(h1buf + (((p - 1) & 1) << 15));
        st_swap2(h4 + bb * (H_ / 4) + (j >> 2), vsel);
      }
    }

    // ---- publish drain -> WG barrier -> flag ----
    WAITVM0();
    __syncthreads();
    if (p < S_ && tid == 0) st_swap(flags + (g << 4), (unsigned)(p + 1));
  }
}

extern "C" void kernel_launch(void* const* d_in, const int* in_sizes, int n_in, void* d_out,
                              int out_size, void* d_ws, size_t ws_size, hipStream_t stream) {
  const int* tokens = (const int*)d_in[0];
  const float* emb = (const float*)d_in[1];
  const float* W0 = (const float*)d_in[2];
  const float* U0 = (const float*)d_in[3];
  const float* b0 = (const float*)d_in[4];
  const float* W1 = (const float*)d_in[5];
  const float* U1 = (const float*)d_in[6];
  const float* b1 = (const float*)d_in[7];
  const float* Wd = (const float*)d_in[8];
  const float* bd = (const float*)d_in[9];
  float* out = (float*)d_out;

  char* ws = (char*)d_ws;
  __hip_bfloat16* Wdt = (__hip_bfloat16*)ws;  ws += (size_t)V_ * H_ * 2;       // 64MB
  __hip_bfloat16* W0t = (__hip_bfloat16*)ws;  ws += (size_t)H_ * E_ * 2;       // 1MB
  __hip_bfloat16* Xg = (__hip_bfloat16*)ws;   ws += (size_t)4096 * E_ * 2;     // 4MB
  __hip_bfloat16* U0f = (__hip_bfloat16*)ws;  ws += (size_t)H_ * H_ * 2;       // 2MB
  __hip_bfloat16* W1f = (__hip_bfloat16*)ws;  ws += (size_t)H_ * H_ * 2;       // 2MB
  __hip_bfloat16* U1f = (__hip_bfloat16*)ws;  ws += (size_t)H_ * H_ * 2;       // 2MB
  float* xw = (float*)ws;                     ws += (size_t)4096 * H_ * 4;     // 16MB
  __hip_bfloat16* h0buf = (__hip_bfloat16*)ws; ws += 2 * B_ * H_ * 2;          // 128KB
  __hip_bfloat16* h1buf = (__hip_bfloat16*)ws; ws += 2 * B_ * H_ * 2;          // 128KB
  __hip_bfloat16* Y = (__hip_bfloat16*)ws;    ws += (size_t)4096 * H_ * 2;     // 8MB
  unsigned* flags = (unsigned*)ws;            ws += 4096;

  // prep
  transpose_f32_bf16<<<dim3(V_ / 32, H_ / 32), 256, 0, stream>>>(Wd, Wdt, H_, V_);
  transpose_f32_bf16<<<dim3(H_ / 32, E_ / 32), 256, 0, stream>>>(W0, W0t, E_, H_);
  gather_embed<<<4096, 256, 0, stream>>>(tokens, emb, Xg);
  make_frag_w<<<512, 256, 0, stream>>>(U0, U0f);
  make_frag_w<<<512, 256, 0, stream>>>(W1, W1f);
  make_frag_w<<<512, 256, 0, stream>>>(U1, U1f);
  hipMemsetAsync(flags, 0, 4096, stream);

  // xw = Xg @ W0 + b0   (M=4096, N=1024, K=512)  — nwg=256, %8==0
  gemm_bf16_tn<<<dim3(H_ / 128, 4096 / 128), 256, 0, stream>>>(Xg, W0t, b0, xw, 4096, H_, E_);

  // recurrence — 48 WGs x 512 threads, co-resident by construction
  rnn_recur<<<NWGS, 512, 0, stream>>>(U0f, W1f, U1f, xw, b1, h0buf, h1buf, Y, flags);

  // logits = Y @ Wd + bd   (M=4096, N=32000, K=1024)  — nwg=8000, %8==0
  gemm_bf16_tn<<<dim3(V_ / 128, 4096 / 128), 256, 0, stream>>>(Y, Wdt, bd, out, 4096, V_, H_);
}

// Round 8
// 1298.427 us; speedup vs baseline: 1.2100x; 1.0625x over previous
//
#include <hip/hip_runtime.h>
#include <hip/hip_bf16.h>
#include <cstdint>

typedef __attribute__((ext_vector_type(8))) short bf16x8;
typedef __attribute__((ext_vector_type(4))) float f32x4;
typedef __attribute__((ext_vector_type(4))) unsigned int u32x4;

#define V_ 32000
#define E_ 512
#define H_ 1024
#define B_ 32
#define S_ 128

#define L1WG 16   // 16 WGs x 64 cols (layer 1)
#define L2WG 32   // 32 WGs x 32 cols (layer 2)
#define NWGS 48

// ---- async global->LDS, 16B per lane (dest = wave-uniform base + lane*16) ----
typedef __attribute__((address_space(1))) unsigned int* gas1_t;
typedef __attribute__((address_space(3))) unsigned int* las3_t;
__device__ __forceinline__ void load_lds16(const void* g, void* l) {
  __builtin_amdgcn_global_load_lds((gas1_t)g, (las3_t)l, 16, 0, 0);
}

// ---- coherent h-state exchange primitives (visibility proven R4/R5/R7) ----
__device__ __forceinline__ void ldx4_sc(u32x4* d, const void* p) {
  asm volatile("global_load_dwordx4 %0, %1, off sc0 sc1" : "=v"(*d) : "v"(p) : "memory");
}
__device__ __forceinline__ unsigned ld_sc(const unsigned* p) {
  unsigned d;
  asm volatile("global_load_dword %0, %1, off sc0 sc1\n\ts_waitcnt vmcnt(0)"
               : "=v"(d) : "v"(p) : "memory");
  return d;
}
__device__ __forceinline__ void st_swap(unsigned* p, unsigned v) {
  asm volatile("global_atomic_swap %0, %1, off sc1" :: "v"(p), "v"(v) : "memory");
}
__device__ __forceinline__ void st_swap2(uint2* p, uint2 v) {
  asm volatile("global_atomic_swap_x2 %0, %1, off sc1" :: "v"(p), "v"(v) : "memory");
}
#define WAITVM0()                                     \
  asm volatile("s_waitcnt vmcnt(0)" ::: "memory");    \
  __builtin_amdgcn_sched_barrier(0)

__device__ __forceinline__ unsigned short bfbits(float x) {
  __hip_bfloat16 b = __float2bfloat16(x);
  union { __hip_bfloat16 b; unsigned short u; } c;
  c.b = b;
  return c.u;
}

// pack 4 rows x 4 cols into one uint2 per lane (2 shfl_xor rounds) — proven R5/R7
__device__ __forceinline__ uint2 pack_rows(const float f[4], int lane, int j) {
  uint2 v2[4];
#pragma unroll
  for (int r = 0; r < 4; ++r) {
    const float o = __shfl_xor(f[r], 1);
    const float lo = (lane & 1) ? o : f[r];
    const float hi = (lane & 1) ? f[r] : o;
    const unsigned pk = (unsigned)bfbits(lo) | ((unsigned)bfbits(hi) << 16);
    const unsigned q2 = __shfl_xor(pk, 2);
    v2[r].x = (j & 2) ? q2 : pk;
    v2[r].y = (j & 2) ? pk : q2;
  }
  const int rs = lane & 3;
  return rs == 0 ? v2[0] : rs == 1 ? v2[1] : rs == 2 ? v2[2] : v2[3];
}

// ---- transpose + f32->bf16 : src[R][C] -> dst[C][R] ----
__global__ __launch_bounds__(256) void transpose_f32_bf16(
    const float* __restrict__ src, __hip_bfloat16* __restrict__ dst, int R, int C) {
  __shared__ float tile[32][33];
  const int c0 = blockIdx.x << 5, r0 = blockIdx.y << 5;
  const int tx = threadIdx.x & 31, ty = threadIdx.x >> 5;
#pragma unroll
  for (int i = 0; i < 32; i += 8)
    tile[ty + i][tx] = src[(size_t)(r0 + ty + i) * C + (c0 + tx)];
  __syncthreads();
#pragma unroll
  for (int i = 0; i < 32; i += 8)
    dst[(size_t)(c0 + ty + i) * R + (r0 + tx)] = __float2bfloat16(tile[tx][ty + i]);
}

// ---- embedding gather -> bf16, rows ordered r = t*32 + b ----
__global__ __launch_bounds__(256) void gather_embed(
    const int* __restrict__ tokens, const float* __restrict__ emb,
    __hip_bfloat16* __restrict__ Xg) {
  const int r = blockIdx.x;
  const int t = r >> 5, b = r & 31;
  const int tok = tokens[b * S_ + t];
  const float* e = emb + (size_t)tok * E_;
  __hip_bfloat16* o = Xg + (size_t)r * E_;
  for (int k = threadIdx.x; k < E_; k += 256) o[k] = __float2bfloat16(e[k]);
}

// ---- [1024][1024] f32 weight -> MFMA B-fragment-linear bf16 ----
__global__ __launch_bounds__(256) void make_frag_w(
    const float* __restrict__ W, __hip_bfloat16* __restrict__ F) {
  const int idx = blockIdx.x * 256 + threadIdx.x;
  const int lane = idx & 63, kb = (idx >> 6) & 31, g = idx >> 11;
  const int j = (g << 4) + (lane & 15);
  const int kbase = (kb << 5) + ((lane >> 4) << 3);
  __hip_bfloat16* o = F + (size_t)idx * 8;
#pragma unroll
  for (int e = 0; e < 8; ++e) o[e] = __float2bfloat16(W[(size_t)(kbase + e) * H_ + j]);
}

// ---- m97-style bf16 MFMA GEMM + bijective XCD swizzle: C = A * Bt^T + bias ----
__global__ __launch_bounds__(256) void gemm_bf16_tn(
    const __hip_bfloat16* __restrict__ A, const __hip_bfloat16* __restrict__ Bt,
    const float* __restrict__ bias, float* __restrict__ C, int M, int N, int K) {
  __shared__ __hip_bfloat16 ldsA[128 * 64];
  __shared__ __hip_bfloat16 ldsB[128 * 64];
  const int nwg = gridDim.x * gridDim.y;
  int L = blockIdx.y * gridDim.x + blockIdx.x;
  L = ((L & 7) * (nwg >> 3)) + (L >> 3);
  const int m0 = (L / gridDim.x) << 7;
  const int n0 = (L % gridDim.x) << 7;
  const int tid = threadIdx.x, wave = tid >> 6, lane = tid & 63;
  const int wr = wave >> 1, wc = wave & 1;
  f32x4 acc[4][4];
#pragma unroll
  for (int i = 0; i < 4; ++i)
#pragma unroll
    for (int jj = 0; jj < 4; ++jj) acc[i][jj] = (f32x4){0.f, 0.f, 0.f, 0.f};

  for (int k0 = 0; k0 < K; k0 += 64) {
#pragma unroll
    for (int i = 0; i < 4; ++i) {
      const int c = i * 4 + wave;
      const int idx = (c << 6) + lane;
      const int row = idx >> 3, kk = (idx & 7) << 3;
      load_lds16(A + (size_t)(m0 + row) * K + (k0 + kk), ldsA + c * 512);
      load_lds16(Bt + (size_t)(n0 + row) * K + (k0 + kk), ldsB + c * 512);
    }
    __syncthreads();
#pragma unroll
    for (int ks = 0; ks < 2; ++ks) {
      bf16x8 af[4], bfr[4];
#pragma unroll
      for (int mi = 0; mi < 4; ++mi)
        af[mi] = *(const bf16x8*)(ldsA + (((wr << 6) + (mi << 4) + (lane & 15)) << 6) +
                                  (ks << 5) + ((lane >> 4) << 3));
#pragma unroll
      for (int ni = 0; ni < 4; ++ni)
        bfr[ni] = *(const bf16x8*)(ldsB + (((wc << 6) + (ni << 4) + (lane & 15)) << 6) +
                                   (ks << 5) + ((lane >> 4) << 3));
#pragma unroll
      for (int mi = 0; mi < 4; ++mi)
#pragma unroll
        for (int ni = 0; ni < 4; ++ni)
          acc[mi][ni] =
              __builtin_amdgcn_mfma_f32_16x16x32_bf16(af[mi], bfr[ni], acc[mi][ni], 0, 0, 0);
    }
    __syncthreads();
  }
#pragma unroll
  for (int mi = 0; mi < 4; ++mi) {
#pragma unroll
    for (int ni = 0; ni < 4; ++ni) {
      const int n = n0 + (wc << 6) + (ni << 4) + (lane & 15);
      const float bn = bias[n];
#pragma unroll
      for (int r = 0; r < 4; ++r) {
        const int m = m0 + (wr << 6) + (mi << 4) + ((lane >> 4) << 2) + r;
        C[(size_t)m * N + n] = acc[mi][ni][r] + bn;
      }
    }
  }
}

// ============================================================================
// Recurrence: 48 WGs x 512 thr, PIPELINED classes with separate flag arrays.
//  L1 (WGs 0..15): phase p computes h0(p); waits L1flags>=p, L2flags>=p-1.
//  L2 (WGs 16..47): step t computes h1(t); waits L1flags>=t+1, L2flags>=t.
//  Race-freedom: h0 slot p&1 overwrites h0(p-2) whose consumers (L1@p-1,
//  L2@t=p-2) are complete under the wait conditions; h1 analogous.
//  LDS A-tiles use ROW-ROTATION swizzle (col' = col + row*64 mod 2048):
//  quarter-wave's 16 rows -> 16 distinct 64B-separated slots (2-way max, free).
// ============================================================================
__global__ __launch_bounds__(512, 2) void rnn_recur(
    const __hip_bfloat16* __restrict__ U0f, const __hip_bfloat16* __restrict__ W1f,
    const __hip_bfloat16* __restrict__ U1f, const float* __restrict__ xw,  // [128][32][1024]
    const float* __restrict__ b1,
    __hip_bfloat16* __restrict__ h0buf,  // [2][32][1024]
    __hip_bfloat16* __restrict__ h1buf,  // [2][32][1024]
    __hip_bfloat16* __restrict__ Y,      // [4096][1024], row = b*128 + t
    unsigned* __restrict__ flags) {      // [48*16] dwords, zeroed before launch
  __shared__ char smem[135168];  // sA0 64KB | sA1 64KB | pad 4KB
  char* sA0 = smem;
  char* sA1 = smem + 65536;
  float* pad = (float*)(smem + 131072);

  const int g = blockIdx.x;
  const bool isL1 = (g < L1WG);
  const int tid = threadIdx.x, wave = tid >> 6, lane = tid & 63;
  const int mi = wave & 1;
  const int cg = isL1 ? (wave >> 1) : ((wave >> 1) & 1);
  const int mat = isL1 ? 0 : (wave >> 2);  // L2: 0 = W1-wave, 1 = U1-wave
  const int colbase = isL1 ? (g << 6) : ((g - L1WG) << 5);
  const int j = colbase + (cg << 4) + (lane & 15);
  const int gg = (colbase >> 4) + cg;  // global 16-col group 0..63
  const int rowbase = (mi << 4) + ((lane >> 4) << 2);
  const int rs = lane & 3;
  const int ra = (mi << 4) + (lane & 15);  // A-frag row this lane reads
  const int q4 = (lane >> 4) << 4;         // k-slice byte offset (0..48)
  const float b1j = b1[j];

  // ---- preload this wave's weight slice into VGPRs (frag-linear, cached) ----
  const __hip_bfloat16* wb = isL1 ? U0f : (mat == 0 ? W1f : U1f);
  bf16x8 wfr[32];
#pragma unroll
  for (int kb = 0; kb < 32; ++kb)
    wfr[kb] = *(const bf16x8*)(wb + (size_t)((((gg << 5) + kb) << 6) + lane) * 8);

  if (!isL1) {  // sA1 <- 0 (h1(-1) == 0)
    for (int i = tid; i < 4096; i += 512) *(uint4*)(sA1 + i * 16) = (uint4){0u, 0u, 0u, 0u};
  }
  __syncthreads();

  // staging address helpers (row-rotation swizzle)
  const int stg_row = tid >> 7;               // +4 per i-iter
  const int stg_colb = (tid & 127) << 4;
  const unsigned* fpoll = flags + ((lane < NWGS ? lane : NWGS - 1) << 4);

  if (isL1) {
    // =========================== layer-1 class ===========================
    for (int p = 0; p < S_; ++p) {
      if (p >= 1) {
        // poll: L1 flags >= p (lanes 0..15), L2 flags >= p-1 (lanes 16..47)
        const unsigned tgt = (lane < L1WG) ? (unsigned)p : (unsigned)(p - 1);
        unsigned v;
        do { v = ld_sc(fpoll); } while (__any(v < tgt));
        // stage h0(p-1) -> sA0 (rotated)
        const char* src0 = (const char*)(h0buf + (((p - 1) & 1) << 15));
        u32x4 t0[8];
#pragma unroll
        for (int i = 0; i < 8; ++i) ldx4_sc(&t0[i], src0 + (size_t)(((i << 9) + tid) << 4));
        WAITVM0();
#pragma unroll
        for (int i = 0; i < 8; ++i) {
          const int row = stg_row + (i << 2);
          *(u32x4*)(sA0 + (row << 11) + ((stg_colb + (row << 6)) & 2047)) = t0[i];
        }
        __syncthreads();
      }
      f32x4 acc = {0.f, 0.f, 0.f, 0.f};
      if (p >= 1) {
#pragma unroll
        for (int kb = 0; kb < 32; ++kb) {
          bf16x8 a = *(const bf16x8*)(
              sA0 + (ra << 11) + (((kb << 6) + q4 + (ra << 6)) & 2047));
          acc = __builtin_amdgcn_mfma_f32_16x16x32_bf16(a, wfr[kb], acc, 0, 0, 0);
        }
      }
      const float* xrow = xw + ((size_t)p << 15);
      float f[4];
#pragma unroll
      for (int r = 0; r < 4; ++r) f[r] = tanhf(acc[r] + xrow[(rowbase + r) * H_ + j]);
      uint2 vsel = pack_rows(f, lane, j);
      uint2* h4 = (uint2*)(h0buf + ((p & 1) << 15));
      st_swap2(h4 + (rowbase + rs) * (H_ / 4) + (j >> 2), vsel);
      WAITVM0();
      __syncthreads();
      if (tid == 0) st_swap(flags + (g << 4), (unsigned)(p + 1));
    }
  } else {
    // =========================== layer-2 class ===========================
    for (int t = 0; t < S_; ++t) {
      // poll: L1 flags >= t+1 (lanes 0..15), L2 flags >= t (lanes 16..47)
      {
        const unsigned tgt = (lane < L1WG) ? (unsigned)(t + 1) : (unsigned)t;
        unsigned v;
        do { v = ld_sc(fpoll); } while (__any(v < tgt));
      }
      // stage h0(t) -> sA0, h1(t-1) -> sA1 (rotated)
      {
        const char* src0 = (const char*)(h0buf + ((t & 1) << 15));
        u32x4 t0[8], t1[8];
#pragma unroll
        for (int i = 0; i < 8; ++i) ldx4_sc(&t0[i], src0 + (size_t)(((i << 9) + tid) << 4));
        if (t >= 1) {
          const char* src1 = (const char*)(h1buf + (((t - 1) & 1) << 15));
#pragma unroll
          for (int i = 0; i < 8; ++i) ldx4_sc(&t1[i], src1 + (size_t)(((i << 9) + tid) << 4));
        }
        WAITVM0();
#pragma unroll
        for (int i = 0; i < 8; ++i) {
          const int row = stg_row + (i << 2);
          *(u32x4*)(sA0 + (row << 11) + ((stg_colb + (row << 6)) & 2047)) = t0[i];
        }
        if (t >= 1) {
#pragma unroll
          for (int i = 0; i < 8; ++i) {
            const int row = stg_row + (i << 2);
            *(u32x4*)(sA1 + (row << 11) + ((stg_colb + (row << 6)) & 2047)) = t1[i];
          }
        }
        __syncthreads();
      }
      // h1(t) = tanh(h0(t)@W1 + h1(t-1)@U1 + b1)
      const char* sA = (mat == 0) ? sA0 : sA1;
      f32x4 acc = {0.f, 0.f, 0.f, 0.f};
#pragma unroll
      for (int kb = 0; kb < 32; ++kb) {
        bf16x8 a = *(const bf16x8*)(
            sA + (ra << 11) + (((kb << 6) + q4 + (ra << 6)) & 2047));
        acc = __builtin_amdgcn_mfma_f32_16x16x32_bf16(a, wfr[kb], acc, 0, 0, 0);
      }
      const int pair = wave & 3;
      if (mat == 0) *(f32x4*)(pad + pair * 256 + lane * 4) = acc;
      __syncthreads();
      if (mat == 1) {
        f32x4 accW = *(const f32x4*)(pad + pair * 256 + lane * 4);
        float f[4];
#pragma unroll
        for (int r = 0; r < 4; ++r) f[r] = tanhf(acc[r] + accW[r] + b1j);
        uint2 vsel = pack_rows(f, lane, j);
        const int bb = rowbase + rs;
        ((uint2*)Y)[((size_t)bb * S_ + t) * (H_ / 4) + (j >> 2)] = vsel;  // cached
        uint2* h4 = (uint2*)(h1buf + ((t & 1) << 15));
        st_swap2(h4 + bb * (H_ / 4) + (j >> 2), vsel);
      }
      WAITVM0();
      __syncthreads();
      if (tid == 0) st_swap(flags + (g << 4), (unsigned)(t + 1));
    }
  }
}

extern "C" void kernel_launch(void* const* d_in, const int* in_sizes, int n_in, void* d_out,
                              int out_size, void* d_ws, size_t ws_size, hipStream_t stream) {
  const int* tokens = (const int*)d_in[0];
  const float* emb = (const float*)d_in[1];
  const float* W0 = (const float*)d_in[2];
  const float* U0 = (const float*)d_in[3];
  const float* b0 = (const float*)d_in[4];
  const float* W1 = (const float*)d_in[5];
  const float* U1 = (const float*)d_in[6];
  const float* b1 = (const float*)d_in[7];
  const float* Wd = (const float*)d_in[8];
  const float* bd = (const float*)d_in[9];
  float* out = (float*)d_out;

  char* ws = (char*)d_ws;
  __hip_bfloat16* Wdt = (__hip_bfloat16*)ws;  ws += (size_t)V_ * H_ * 2;       // 64MB
  __hip_bfloat16* W0t = (__hip_bfloat16*)ws;  ws += (size_t)H_ * E_ * 2;       // 1MB
  __hip_bfloat16* Xg = (__hip_bfloat16*)ws;   ws += (size_t)4096 * E_ * 2;     // 4MB
  __hip_bfloat16* U0f = (__hip_bfloat16*)ws;  ws += (size_t)H_ * H_ * 2;       // 2MB
  __hip_bfloat16* W1f = (__hip_bfloat16*)ws;  ws += (size_t)H_ * H_ * 2;       // 2MB
  __hip_bfloat16* U1f = (__hip_bfloat16*)ws;  ws += (size_t)H_ * H_ * 2;       // 2MB
  float* xw = (float*)ws;                     ws += (size_t)4096 * H_ * 4;     // 16MB
  __hip_bfloat16* h0buf = (__hip_bfloat16*)ws; ws += 2 * B_ * H_ * 2;          // 128KB
  __hip_bfloat16* h1buf = (__hip_bfloat16*)ws; ws += 2 * B_ * H_ * 2;          // 128KB
  __hip_bfloat16* Y = (__hip_bfloat16*)ws;    ws += (size_t)4096 * H_ * 2;     // 8MB
  unsigned* flags = (unsigned*)ws;            ws += 4096;

  // prep
  transpose_f32_bf16<<<dim3(V_ / 32, H_ / 32), 256, 0, stream>>>(Wd, Wdt, H_, V_);
  transpose_f32_bf16<<<dim3(H_ / 32, E_ / 32), 256, 0, stream>>>(W0, W0t, E_, H_);
  gather_embed<<<4096, 256, 0, stream>>>(tokens, emb, Xg);
  make_frag_w<<<512, 256, 0, stream>>>(U0, U0f);
  make_frag_w<<<512, 256, 0, stream>>>(W1, W1f);
  make_frag_w<<<512, 256, 0, stream>>>(U1, U1f);
  hipMemsetAsync(flags, 0, 4096, stream);

  // xw = Xg @ W0 + b0   (M=4096, N=1024, K=512)  — nwg=256, %8==0
  gemm_bf16_tn<<<dim3(H_ / 128, 4096 / 128), 256, 0, stream>>>(Xg, W0t, b0, xw, 4096, H_, E_);

  // recurrence — pipelined L1/L2 classes, 48 WGs x 512 threads
  rnn_recur<<<NWGS, 512, 0, stream>>>(U0f, W1f, U1f, xw, b1, h0buf, h1buf, Y, flags);

  // logits = Y @ Wd + bd   (M=4096, N=32000, K=1024)  — nwg=8000, %8==0
  gemm_bf16_tn<<<dim3(V_ / 128, 4096 / 128), 256, 0, stream>>>(Y, Wdt, bd, out, 4096, V_, H_);
}

// Round 9
// 1263.000 us; speedup vs baseline: 1.2440x; 1.0281x over previous
//
#include <hip/hip_runtime.h>
#include <hip/hip_bf16.h>
#include <cstdint>

typedef __attribute__((ext_vector_type(8))) short bf16x8;
typedef __attribute__((ext_vector_type(4))) float f32x4;
typedef __attribute__((ext_vector_type(4))) unsigned int u32x4;

#define V_ 32000
#define E_ 512
#define H_ 1024
#define B_ 32
#define S_ 128

#define L1WG 16   // 16 WGs x 64 cols (layer 1)
#define L2WG 32   // 32 WGs x 32 cols (layer 2)
#define NWGS 48

// ---- async global->LDS, 16B per lane (dest = wave-uniform base + lane*16) ----
typedef __attribute__((address_space(1))) unsigned int* gas1_t;
typedef __attribute__((address_space(3))) unsigned int* las3_t;
__device__ __forceinline__ void load_lds16(const void* g, void* l) {
  __builtin_amdgcn_global_load_lds((gas1_t)g, (las3_t)l, 16, 0, 0);
}

// ---- coherent h-state exchange primitives (visibility proven R4/R5/R7/R8) ----
__device__ __forceinline__ void ldx4_sc(u32x4* d, const void* p) {
  asm volatile("global_load_dwordx4 %0, %1, off sc0 sc1" : "=v"(*d) : "v"(p) : "memory");
}
__device__ __forceinline__ unsigned ld_sc(const unsigned* p) {
  unsigned d;
  asm volatile("global_load_dword %0, %1, off sc0 sc1\n\ts_waitcnt vmcnt(0)"
               : "=v"(d) : "v"(p) : "memory");
  return d;
}
__device__ __forceinline__ void st_swap(unsigned* p, unsigned v) {
  asm volatile("global_atomic_swap %0, %1, off sc1" :: "v"(p), "v"(v) : "memory");
}
__device__ __forceinline__ void st_swap2(uint2* p, uint2 v) {
  asm volatile("global_atomic_swap_x2 %0, %1, off sc1" :: "v"(p), "v"(v) : "memory");
}
#define WAITVM0()                                     \
  asm volatile("s_waitcnt vmcnt(0)" ::: "memory");    \
  __builtin_amdgcn_sched_barrier(0)

__device__ __forceinline__ unsigned short bfbits(float x) {
  __hip_bfloat16 b = __float2bfloat16(x);
  union { __hip_bfloat16 b; unsigned short u; } c;
  c.b = b;
  return c.u;
}

// pack 4 rows x 4 cols into one uint2 per lane (2 shfl_xor rounds) — proven R5+
__device__ __forceinline__ uint2 pack_rows(const float f[4], int lane, int j) {
  uint2 v2[4];
#pragma unroll
  for (int r = 0; r < 4; ++r) {
    const float o = __shfl_xor(f[r], 1);
    const float lo = (lane & 1) ? o : f[r];
    const float hi = (lane & 1) ? f[r] : o;
    const unsigned pk = (unsigned)bfbits(lo) | ((unsigned)bfbits(hi) << 16);
    const unsigned q2 = __shfl_xor(pk, 2);
    v2[r].x = (j & 2) ? q2 : pk;
    v2[r].y = (j & 2) ? pk : q2;
  }
  const int rs = lane & 3;
  return rs == 0 ? v2[0] : rs == 1 ? v2[1] : rs == 2 ? v2[2] : v2[3];
}

// ---- transpose + f32->bf16 : src[R][C] -> dst[C][R] ----
__global__ __launch_bounds__(256) void transpose_f32_bf16(
    const float* __restrict__ src, __hip_bfloat16* __restrict__ dst, int R, int C) {
  __shared__ float tile[32][33];
  const int c0 = blockIdx.x << 5, r0 = blockIdx.y << 5;
  const int tx = threadIdx.x & 31, ty = threadIdx.x >> 5;
#pragma unroll
  for (int i = 0; i < 32; i += 8)
    tile[ty + i][tx] = src[(size_t)(r0 + ty + i) * C + (c0 + tx)];
  __syncthreads();
#pragma unroll
  for (int i = 0; i < 32; i += 8)
    dst[(size_t)(c0 + ty + i) * R + (r0 + tx)] = __float2bfloat16(tile[tx][ty + i]);
}

// ---- embedding gather -> bf16, rows ordered r = t*32 + b ----
__global__ __launch_bounds__(256) void gather_embed(
    const int* __restrict__ tokens, const float* __restrict__ emb,
    __hip_bfloat16* __restrict__ Xg) {
  const int r = blockIdx.x;
  const int t = r >> 5, b = r & 31;
  const int tok = tokens[b * S_ + t];
  const float* e = emb + (size_t)tok * E_;
  __hip_bfloat16* o = Xg + (size_t)r * E_;
  for (int k = threadIdx.x; k < E_; k += 256) o[k] = __float2bfloat16(e[k]);
}

// ---- [1024][1024] f32 weight -> MFMA B-fragment-linear bf16 ----
__global__ __launch_bounds__(256) void make_frag_w(
    const float* __restrict__ W, __hip_bfloat16* __restrict__ F) {
  const int idx = blockIdx.x * 256 + threadIdx.x;
  const int lane = idx & 63, kb = (idx >> 6) & 31, g = idx >> 11;
  const int j = (g << 4) + (lane & 15);
  const int kbase = (kb << 5) + ((lane >> 4) << 3);
  __hip_bfloat16* o = F + (size_t)idx * 8;
#pragma unroll
  for (int e = 0; e < 8; ++e) o[e] = __float2bfloat16(W[(size_t)(kbase + e) * H_ + j]);
}

// ---- m97-style bf16 MFMA GEMM + bijective XCD swizzle: C = A * Bt^T + bias ----
__global__ __launch_bounds__(256) void gemm_bf16_tn(
    const __hip_bfloat16* __restrict__ A, const __hip_bfloat16* __restrict__ Bt,
    const float* __restrict__ bias, float* __restrict__ C, int M, int N, int K) {
  __shared__ __hip_bfloat16 ldsA[128 * 64];
  __shared__ __hip_bfloat16 ldsB[128 * 64];
  const int nwg = gridDim.x * gridDim.y;
  int L = blockIdx.y * gridDim.x + blockIdx.x;
  L = ((L & 7) * (nwg >> 3)) + (L >> 3);
  const int m0 = (L / gridDim.x) << 7;
  const int n0 = (L % gridDim.x) << 7;
  const int tid = threadIdx.x, wave = tid >> 6, lane = tid & 63;
  const int wr = wave >> 1, wc = wave & 1;
  f32x4 acc[4][4];
#pragma unroll
  for (int i = 0; i < 4; ++i)
#pragma unroll
    for (int jj = 0; jj < 4; ++jj) acc[i][jj] = (f32x4){0.f, 0.f, 0.f, 0.f};

  for (int k0 = 0; k0 < K; k0 += 64) {
#pragma unroll
    for (int i = 0; i < 4; ++i) {
      const int c = i * 4 + wave;
      const int idx = (c << 6) + lane;
      const int row = idx >> 3, kk = (idx & 7) << 3;
      load_lds16(A + (size_t)(m0 + row) * K + (k0 + kk), ldsA + c * 512);
      load_lds16(Bt + (size_t)(n0 + row) * K + (k0 + kk), ldsB + c * 512);
    }
    __syncthreads();
#pragma unroll
    for (int ks = 0; ks < 2; ++ks) {
      bf16x8 af[4], bfr[4];
#pragma unroll
      for (int mi = 0; mi < 4; ++mi)
        af[mi] = *(const bf16x8*)(ldsA + (((wr << 6) + (mi << 4) + (lane & 15)) << 6) +
                                  (ks << 5) + ((lane >> 4) << 3));
#pragma unroll
      for (int ni = 0; ni < 4; ++ni)
        bfr[ni] = *(const bf16x8*)(ldsB + (((wc << 6) + (ni << 4) + (lane & 15)) << 6) +
                                   (ks << 5) + ((lane >> 4) << 3));
#pragma unroll
      for (int mi = 0; mi < 4; ++mi)
#pragma unroll
        for (int ni = 0; ni < 4; ++ni)
          acc[mi][ni] =
              __builtin_amdgcn_mfma_f32_16x16x32_bf16(af[mi], bfr[ni], acc[mi][ni], 0, 0, 0);
    }
    __syncthreads();
  }
#pragma unroll
  for (int mi = 0; mi < 4; ++mi) {
#pragma unroll
    for (int ni = 0; ni < 4; ++ni) {
      const int n = n0 + (wc << 6) + (ni << 4) + (lane & 15);
      const float bn = bias[n];
#pragma unroll
      for (int r = 0; r < 4; ++r) {
        const int m = m0 + (wr << 6) + (mi << 4) + ((lane >> 4) << 2) + r;
        C[(size_t)m * N + n] = acc[mi][ni][r] + bn;
      }
    }
  }
}

// ============================================================================
// Recurrence: 48 WGs x 512 thr, DECOUPLED pipeline via h0 ring-depth 4.
//  h0buf = [4][32][1024]  (slot p&3);  h1buf = [2][32][1024] (slot t&1).
//  L1 (WGs 0..15): step p waits {L1 flags >= p, L2 flags >= p-3}.
//    -> overwrite target h0(p-4): L2 staged it at step p-4 (flag p-3). safe.
//    -> 3-step cushion removes L1<->L2 cycle; period -> max(member).
//  L2 (WGs 16..47): step t waits {L1 flags >= t+1, L2 flags >= t}.
//  xw values prefetched before the poll (flag-independent).
//  LDS swizzle: XOR form (R7) — 2-way max on A-frag reads.
// ============================================================================
__global__ __launch_bounds__(512, 2) void rnn_recur(
    const __hip_bfloat16* __restrict__ U0f, const __hip_bfloat16* __restrict__ W1f,
    const __hip_bfloat16* __restrict__ U1f, const float* __restrict__ xw,  // [128][32][1024]
    const float* __restrict__ b1,
    __hip_bfloat16* __restrict__ h0buf,  // [4][32][1024]
    __hip_bfloat16* __restrict__ h1buf,  // [2][32][1024]
    __hip_bfloat16* __restrict__ Y,      // [4096][1024], row = b*128 + t
    unsigned* __restrict__ flags) {      // [48*16] dwords, zeroed before launch
  __shared__ char smem[135168];  // sA0 64KB | sA1 64KB | pad 4KB
  char* sA0 = smem;
  char* sA1 = smem + 65536;
  float* pad = (float*)(smem + 131072);

  const int g = blockIdx.x;
  const bool isL1 = (g < L1WG);
  const int tid = threadIdx.x, wave = tid >> 6, lane = tid & 63;
  const int mi = wave & 1;
  const int cg = isL1 ? (wave >> 1) : ((wave >> 1) & 1);
  const int mat = isL1 ? 0 : (wave >> 2);  // L2: 0 = W1-wave, 1 = U1-wave
  const int colbase = isL1 ? (g << 6) : ((g - L1WG) << 5);
  const int j = colbase + (cg << 4) + (lane & 15);
  const int gg = (colbase >> 4) + cg;  // global 16-col group 0..63
  const int rowbase = (mi << 4) + ((lane >> 4) << 2);
  const int rs = lane & 3;
  const int ra = (mi << 4) + (lane & 15);  // A-frag row this lane reads
  const int q4 = (lane >> 4) << 4;         // k-slice byte offset (0..48)
  const float b1j = b1[j];

  // ---- preload this wave's weight slice into VGPRs (frag-linear, cached) ----
  const __hip_bfloat16* wb = isL1 ? U0f : (mat == 0 ? W1f : U1f);
  bf16x8 wfr[32];
#pragma unroll
  for (int kb = 0; kb < 32; ++kb)
    wfr[kb] = *(const bf16x8*)(wb + (size_t)((((gg << 5) + kb) << 6) + lane) * 8);

  if (!isL1) {  // sA1 <- 0 (h1(-1) == 0)
    for (int i = tid; i < 4096; i += 512) *(uint4*)(sA1 + i * 16) = (uint4){0u, 0u, 0u, 0u};
  }
  __syncthreads();

  const int stg_row = tid >> 7;               // +4 per i-iter
  const int stg_colb = (tid & 127) << 4;
  const unsigned* fpoll = flags + ((lane < NWGS ? lane : NWGS - 1) << 4);

  if (isL1) {
    // =========================== layer-1 class ===========================
    for (int p = 0; p < S_; ++p) {
      // xw prefetch — flag-independent, issued before the poll
      const float* xrow = xw + ((size_t)p << 15);
      float xv[4];
#pragma unroll
      for (int r = 0; r < 4; ++r) xv[r] = xrow[(rowbase + r) * H_ + j];
      if (p >= 1) {
        // poll: L1 flags >= p ; L2 flags >= p-3 (ring-4 cushion)
        const unsigned tgt =
            (lane < L1WG) ? (unsigned)p : (p >= 3 ? (unsigned)(p - 3) : 0u);
        unsigned v;
        do { v = ld_sc(fpoll); } while (__any(v < tgt));
        // stage h0(p-1) -> sA0 (XOR swizzle)
        const char* src0 = (const char*)(h0buf + ((size_t)((p - 1) & 3) << 15));
        u32x4 t0[8];
#pragma unroll
        for (int i = 0; i < 8; ++i) ldx4_sc(&t0[i], src0 + (size_t)(((i << 9) + tid) << 4));
        WAITVM0();
#pragma unroll
        for (int i = 0; i < 8; ++i) {
          const int row = stg_row + (i << 2);
          *(u32x4*)(sA0 + (row << 11) + (stg_colb ^ ((row & 7) << 4))) = t0[i];
        }
        __syncthreads();
      }
      f32x4 acc = {0.f, 0.f, 0.f, 0.f};
      if (p >= 1) {
#pragma unroll
        for (int kb = 0; kb < 32; ++kb) {
          bf16x8 a = *(const bf16x8*)(
              sA0 + (ra << 11) + ((((kb << 6) + q4)) ^ ((ra & 7) << 4)));
          acc = __builtin_amdgcn_mfma_f32_16x16x32_bf16(a, wfr[kb], acc, 0, 0, 0);
        }
      }
      float f[4];
#pragma unroll
      for (int r = 0; r < 4; ++r) f[r] = tanhf(acc[r] + xv[r]);
      uint2 vsel = pack_rows(f, lane, j);
      uint2* h4 = (uint2*)(h0buf + ((size_t)(p & 3) << 15));
      st_swap2(h4 + (rowbase + rs) * (H_ / 4) + (j >> 2), vsel);
      WAITVM0();
      __syncthreads();
      if (tid == 0) st_swap(flags + (g << 4), (unsigned)(p + 1));
    }
  } else {
    // =========================== layer-2 class ===========================
    for (int t = 0; t < S_; ++t) {
      // poll: L1 flags >= t+1 ; L2 flags >= t
      {
        const unsigned tgt = (lane < L1WG) ? (unsigned)(t + 1) : (unsigned)t;
        unsigned v;
        do { v = ld_sc(fpoll); } while (__any(v < tgt));
      }
      // stage h0(t) -> sA0, h1(t-1) -> sA1 (XOR swizzle)
      {
        const char* src0 = (const char*)(h0buf + ((size_t)(t & 3) << 15));
        u32x4 t0[8], t1[8];
#pragma unroll
        for (int i = 0; i < 8; ++i) ldx4_sc(&t0[i], src0 + (size_t)(((i << 9) + tid) << 4));
        if (t >= 1) {
          const char* src1 = (const char*)(h1buf + ((size_t)((t - 1) & 1) << 15));
#pragma unroll
          for (int i = 0; i < 8; ++i) ldx4_sc(&t1[i], src1 + (size_t)(((i << 9) + tid) << 4));
        }
        WAITVM0();
#pragma unroll
        for (int i = 0; i < 8; ++i) {
          const int row = stg_row + (i << 2);
          *(u32x4*)(sA0 + (row << 11) + (stg_colb ^ ((row & 7) << 4))) = t0[i];
        }
        if (t >= 1) {
#pragma unroll
          for (int i = 0; i < 8; ++i) {
            const int row = stg_row + (i << 2);
            *(u32x4*)(sA1 + (row << 11) + (stg_colb ^ ((row & 7) << 4))) = t1[i];
          }
        }
        __syncthreads();
      }
      // h1(t) = tanh(h0(t)@W1 + h1(t-1)@U1 + b1)
      const char* sA = (mat == 0) ? sA0 : sA1;
      f32x4 acc = {0.f, 0.f, 0.f, 0.f};
#pragma unroll
      for (int kb = 0; kb < 32; ++kb) {
        bf16x8 a = *(const bf16x8*)(
            sA + (ra << 11) + ((((kb << 6) + q4)) ^ ((ra & 7) << 4)));
        acc = __builtin_amdgcn_mfma_f32_16x16x32_bf16(a, wfr[kb], acc, 0, 0, 0);
      }
      const int pair = wave & 3;
      if (mat == 0) *(f32x4*)(pad + pair * 256 + lane * 4) = acc;
      __syncthreads();
      if (mat == 1) {
        f32x4 accW = *(const f32x4*)(pad + pair * 256 + lane * 4);
        float f[4];
#pragma unroll
        for (int r = 0; r < 4; ++r) f[r] = tanhf(acc[r] + accW[r] + b1j);
        uint2 vsel = pack_rows(f, lane, j);
        const int bb = rowbase + rs;
        ((uint2*)Y)[((size_t)bb * S_ + t) * (H_ / 4) + (j >> 2)] = vsel;  // cached
        uint2* h4 = (uint2*)(h1buf + ((size_t)(t & 1) << 15));
        st_swap2(h4 + bb * (H_ / 4) + (j >> 2), vsel);
      }
      WAITVM0();
      __syncthreads();
      if (tid == 0) st_swap(flags + (g << 4), (unsigned)(t + 1));
    }
  }
}

extern "C" void kernel_launch(void* const* d_in, const int* in_sizes, int n_in, void* d_out,
                              int out_size, void* d_ws, size_t ws_size, hipStream_t stream) {
  const int* tokens = (const int*)d_in[0];
  const float* emb = (const float*)d_in[1];
  const float* W0 = (const float*)d_in[2];
  const float* U0 = (const float*)d_in[3];
  const float* b0 = (const float*)d_in[4];
  const float* W1 = (const float*)d_in[5];
  const float* U1 = (const float*)d_in[6];
  const float* b1 = (const float*)d_in[7];
  const float* Wd = (const float*)d_in[8];
  const float* bd = (const float*)d_in[9];
  float* out = (float*)d_out;

  char* ws = (char*)d_ws;
  __hip_bfloat16* Wdt = (__hip_bfloat16*)ws;  ws += (size_t)V_ * H_ * 2;       // 64MB
  __hip_bfloat16* W0t = (__hip_bfloat16*)ws;  ws += (size_t)H_ * E_ * 2;       // 1MB
  __hip_bfloat16* Xg = (__hip_bfloat16*)ws;   ws += (size_t)4096 * E_ * 2;     // 4MB
  __hip_bfloat16* U0f = (__hip_bfloat16*)ws;  ws += (size_t)H_ * H_ * 2;       // 2MB
  __hip_bfloat16* W1f = (__hip_bfloat16*)ws;  ws += (size_t)H_ * H_ * 2;       // 2MB
  __hip_bfloat16* U1f = (__hip_bfloat16*)ws;  ws += (size_t)H_ * H_ * 2;       // 2MB
  float* xw = (float*)ws;                     ws += (size_t)4096 * H_ * 4;     // 16MB
  __hip_bfloat16* h0buf = (__hip_bfloat16*)ws; ws += 4 * B_ * H_ * 2;          // 256KB (ring-4)
  __hip_bfloat16* h1buf = (__hip_bfloat16*)ws; ws += 2 * B_ * H_ * 2;          // 128KB
  __hip_bfloat16* Y = (__hip_bfloat16*)ws;    ws += (size_t)4096 * H_ * 2;     // 8MB
  unsigned* flags = (unsigned*)ws;            ws += 4096;

  // prep
  transpose_f32_bf16<<<dim3(V_ / 32, H_ / 32), 256, 0, stream>>>(Wd, Wdt, H_, V_);
  transpose_f32_bf16<<<dim3(H_ / 32, E_ / 32), 256, 0, stream>>>(W0, W0t, E_, H_);
  gather_embed<<<4096, 256, 0, stream>>>(tokens, emb, Xg);
  make_frag_w<<<512, 256, 0, stream>>>(U0, U0f);
  make_frag_w<<<512, 256, 0, stream>>>(W1, W1f);
  make_frag_w<<<512, 256, 0, stream>>>(U1, U1f);
  hipMemsetAsync(flags, 0, 4096, stream);

  // xw = Xg @ W0 + b0   (M=4096, N=1024, K=512)  — nwg=256, %8==0
  gemm_bf16_tn<<<dim3(H_ / 128, 4096 / 128), 256, 0, stream>>>(Xg, W0t, b0, xw, 4096, H_, E_);

  // recurrence — decoupled pipelined classes, 48 WGs x 512 threads
  rnn_recur<<<NWGS, 512, 0, stream>>>(U0f, W1f, U1f, xw, b1, h0buf, h1buf, Y, flags);

  // logits = Y @ Wd + bd   (M=4096, N=32000, K=1024)  — nwg=8000, %8==0
  gemm_bf16_tn<<<dim3(V_ / 128, 4096 / 128), 256, 0, stream>>>(Y, Wdt, bd, out, 4096, V_, H_);
}